// Round 2
// baseline (260.469 us; speedup 1.0000x reference)
//
#include <hip/hip_runtime.h>
#include <cmath>

// B=64, S=2048, H=1024 fp32 attention + combine linear.
// lstm_output (512 MiB) dominates -> single-pass online softmax, read once.
// Round 2: pass1 = 2 rows/iter + explicit pair prefetch + deferred rescale;
//          pass3 = W-row-in-registers, coalesced X reads, shuffle reduce.

namespace {
constexpr int B = 64;
constexpr int S = 2048;
constexpr int H = 1024;
constexpr int PSTRIDE = H + 4;   // floats per partial record (16B aligned)
}

// ---------------- Pass 1: fused scores + online softmax + weighted sum ------
#define LOADPAIR(RA, RB, P) do {                                               \
    const float4* _q = base4 + (size_t)(P) * 512;                              \
    _Pragma("unroll")                                                          \
    for (int j = 0; j < 4; ++j) RA[j] = _q[lane + 64 * j];                     \
    _Pragma("unroll")                                                          \
    for (int j = 0; j < 4; ++j) RB[j] = _q[256 + lane + 64 * j];               \
} while (0)

#define COMPUTE(RA, RB) do {                                                   \
    float d0 = 0.f, d1 = 0.f, e0 = 0.f, e1 = 0.f;                              \
    _Pragma("unroll")                                                          \
    for (int j = 0; j < 2; ++j) {                                              \
        d0 = fmaf(RA[j].x, hv[j].x, d0);   d0 = fmaf(RA[j].y, hv[j].y, d0);    \
        d0 = fmaf(RA[j].z, hv[j].z, d0);   d0 = fmaf(RA[j].w, hv[j].w, d0);    \
        e0 = fmaf(RA[j+2].x, hv[j+2].x, e0); e0 = fmaf(RA[j+2].y, hv[j+2].y, e0);\
        e0 = fmaf(RA[j+2].z, hv[j+2].z, e0); e0 = fmaf(RA[j+2].w, hv[j+2].w, e0);\
        d1 = fmaf(RB[j].x, hv[j].x, d1);   d1 = fmaf(RB[j].y, hv[j].y, d1);    \
        d1 = fmaf(RB[j].z, hv[j].z, d1);   d1 = fmaf(RB[j].w, hv[j].w, d1);    \
        e1 = fmaf(RB[j+2].x, hv[j+2].x, e1); e1 = fmaf(RB[j+2].y, hv[j+2].y, e1);\
        e1 = fmaf(RB[j+2].z, hv[j+2].z, e1); e1 = fmaf(RB[j+2].w, hv[j+2].w, e1);\
    }                                                                          \
    d0 += e0; d1 += e1;                                                        \
    _Pragma("unroll")                                                          \
    for (int off = 32; off >= 1; off >>= 1) {                                  \
        d0 += __shfl_xor(d0, off);                                             \
        d1 += __shfl_xor(d1, off);                                             \
    }                                                                          \
    const float mx = fmaxf(d0, d1);                                            \
    if (mx > m) {   /* wave-uniform branch: d0,d1 uniform after butterfly */   \
        const float sc = __expf(m - mx);                                       \
        l *= sc;                                                               \
        _Pragma("unroll")                                                      \
        for (int j = 0; j < 4; ++j) {                                          \
            acc[j].x *= sc; acc[j].y *= sc; acc[j].z *= sc; acc[j].w *= sc;    \
        }                                                                      \
        m = mx;                                                                \
    }                                                                          \
    const float p0 = __expf(d0 - m);                                           \
    const float p1 = __expf(d1 - m);                                           \
    l += p0 + p1;                                                              \
    _Pragma("unroll")                                                          \
    for (int j = 0; j < 4; ++j) {                                              \
        acc[j].x = fmaf(p0, RA[j].x, acc[j].x); acc[j].x = fmaf(p1, RB[j].x, acc[j].x); \
        acc[j].y = fmaf(p0, RA[j].y, acc[j].y); acc[j].y = fmaf(p1, RB[j].y, acc[j].y); \
        acc[j].z = fmaf(p0, RA[j].z, acc[j].z); acc[j].z = fmaf(p1, RB[j].z, acc[j].z); \
        acc[j].w = fmaf(p0, RA[j].w, acc[j].w); acc[j].w = fmaf(p1, RB[j].w, acc[j].w); \
    }                                                                          \
} while (0)

__global__ __launch_bounds__(256, 4) void attn_pass1(
    const float* __restrict__ lstm,
    const float* __restrict__ hidden,
    float* __restrict__ ws,
    int chunk)                       // rows per block
{
    const int c    = blockIdx.x;
    const int b    = blockIdx.y;
    const int tid  = threadIdx.x;
    const int w    = tid >> 6;
    const int lane = tid & 63;

    const float4* hid4 = reinterpret_cast<const float4*>(hidden + (size_t)b * H);
    float4 hv[4];
#pragma unroll
    for (int j = 0; j < 4; ++j) hv[j] = hid4[lane + 64 * j];

    const int rows_per_wave = chunk >> 2;        // 4 waves/block
    const int npairs = rows_per_wave >> 1;       // even, >= 2
    const int row0 = c * chunk + w * rows_per_wave;
    const float4* base4 =
        reinterpret_cast<const float4*>(lstm + ((size_t)b * S + row0) * H);

    float m = -INFINITY, l = 0.0f;
    float4 acc[4];
#pragma unroll
    for (int j = 0; j < 4; ++j) acc[j] = make_float4(0.f, 0.f, 0.f, 0.f);

    float4 ra[4], rb[4], na[4], nb[4];

    LOADPAIR(ra, rb, 0);
    int p = 0;
    for (; p + 2 < npairs; p += 2) {
        LOADPAIR(na, nb, p + 1);     // prefetch while computing current
        COMPUTE(ra, rb);
        LOADPAIR(ra, rb, p + 2);
        COMPUTE(na, nb);
    }
    LOADPAIR(na, nb, npairs - 1);
    COMPUTE(ra, rb);
    COMPUTE(na, nb);

    // ---- combine the 4 waves of this block ----
    __shared__ float red_m[4];
    __shared__ float red_l[4];
    __shared__ float4 accbuf[4 * 256];           // 16 KiB

    if (lane == 0) { red_m[w] = m; red_l[w] = l; }
    __syncthreads();

    const float M = fmaxf(fmaxf(red_m[0], red_m[1]), fmaxf(red_m[2], red_m[3]));
    const float sc = __expf(m - M);
#pragma unroll
    for (int j = 0; j < 4; ++j) {
        float4 a = acc[j];
        accbuf[w * 256 + lane + 64 * j] =
            make_float4(a.x * sc, a.y * sc, a.z * sc, a.w * sc);
    }
    __syncthreads();

    const float L = red_l[0] * __expf(red_m[0] - M)
                  + red_l[1] * __expf(red_m[1] - M)
                  + red_l[2] * __expf(red_m[2] - M)
                  + red_l[3] * __expf(red_m[3] - M);

    const int nsplit = gridDim.x;
    float* part = ws + (size_t)(b * nsplit + c) * PSTRIDE;
    float4 s4 = accbuf[tid];
    {
        float4 t1 = accbuf[256 + tid];
        float4 t2 = accbuf[512 + tid];
        float4 t3 = accbuf[768 + tid];
        s4.x += t1.x + t2.x + t3.x;
        s4.y += t1.y + t2.y + t3.y;
        s4.z += t1.z + t2.z + t3.z;
        s4.w += t1.w + t2.w + t3.w;
    }
    reinterpret_cast<float4*>(part)[tid] = s4;
    if (tid == 0) { part[H] = M; part[H + 1] = L; }
}

// ---------------- Pass 2: merge nsplit partials per batch -------------------
__global__ __launch_bounds__(256) void attn_pass2(
    const float* __restrict__ ws, int nsplit, float* __restrict__ attn)
{
    const int b   = blockIdx.x;
    const int tid = threadIdx.x;

    __shared__ float sm[32];
    __shared__ float sl[32];
    if (tid < nsplit) {
        const float* part = ws + (size_t)(b * nsplit + tid) * PSTRIDE;
        sm[tid] = part[H];
        sl[tid] = part[H + 1];
    }
    __syncthreads();

    float M = -INFINITY;
    for (int i = 0; i < nsplit; ++i) M = fmaxf(M, sm[i]);
    float L = 0.0f;
    for (int i = 0; i < nsplit; ++i) L = fmaf(sl[i], __expf(sm[i] - M), L);
    const float inv = 1.0f / L;

    float4 a = make_float4(0.f, 0.f, 0.f, 0.f);
    for (int i = 0; i < nsplit; ++i) {
        const float f = __expf(sm[i] - M);    // recompute: avoids scratch array
        float4 v = reinterpret_cast<const float4*>(
            ws + (size_t)(b * nsplit + i) * PSTRIDE)[tid];
        a.x = fmaf(v.x, f, a.x);
        a.y = fmaf(v.y, f, a.y);
        a.z = fmaf(v.z, f, a.z);
        a.w = fmaf(v.w, f, a.w);
    }
    reinterpret_cast<float4*>(attn)[(size_t)b * (H / 4) + tid] =
        make_float4(a.x * inv, a.y * inv, a.z * inv, a.w * inv);
}

// ---------------- Pass 3: out = [hidden, attn] @ W^T + bias -----------------
// Wave = one output feature, W-row in 32 VGPRs; lanes span k (coalesced,
// L2-hot X reads); butterfly reduce per (o,b).
__global__ __launch_bounds__(512) void attn_pass3(
    const float* __restrict__ hidden,
    const float* __restrict__ W,        // [H, 2H] row-major
    const float* __restrict__ bias,
    const float* __restrict__ attn,     // [B, H]
    float* __restrict__ out)            // [B, H]
{
    const int tid  = threadIdx.x;
    const int wid  = tid >> 6;
    const int lane = tid & 63;
    const int o    = blockIdx.x * 8 + wid;

    const float4* W4 = reinterpret_cast<const float4*>(W + (size_t)o * (2 * H));
    float4 wv[8];
#pragma unroll
    for (int j = 0; j < 8; ++j) wv[j] = W4[lane + 64 * j];
    const float bo = bias[o];

    for (int b = 0; b < B; ++b) {
        const float4* h4 = reinterpret_cast<const float4*>(hidden + (size_t)b * H);
        const float4* a4 = reinterpret_cast<const float4*>(attn + (size_t)b * H);
        float s0 = 0.f, s1 = 0.f;
#pragma unroll
        for (int j = 0; j < 4; ++j) {
            float4 x = h4[lane + 64 * j];
            s0 = fmaf(x.x, wv[j].x, s0);
            s0 = fmaf(x.y, wv[j].y, s0);
            s0 = fmaf(x.z, wv[j].z, s0);
            s0 = fmaf(x.w, wv[j].w, s0);
            float4 y = a4[lane + 64 * j];
            s1 = fmaf(y.x, wv[j + 4].x, s1);
            s1 = fmaf(y.y, wv[j + 4].y, s1);
            s1 = fmaf(y.z, wv[j + 4].z, s1);
            s1 = fmaf(y.w, wv[j + 4].w, s1);
        }
        float s = s0 + s1;
#pragma unroll
        for (int off = 32; off >= 1; off >>= 1) s += __shfl_xor(s, off);
        if (lane == 0) out[(size_t)b * H + o] = s + bo;
    }
}

extern "C" void kernel_launch(void* const* d_in, const int* in_sizes, int n_in,
                              void* d_out, int out_size, void* d_ws, size_t ws_size,
                              hipStream_t stream)
{
    const float* lstm   = (const float*)d_in[0];  // [B,S,H]
    const float* hidden = (const float*)d_in[1];  // [B,H]
    const float* W      = (const float*)d_in[2];  // [H,2H]
    const float* bias   = (const float*)d_in[3];  // [H]
    float* out = (float*)d_out;                   // [B,H]
    float* ws  = (float*)d_ws;

    // pick largest split that fits the workspace
    int nsplit = 32;
    while (nsplit > 8) {
        size_t need = ((size_t)nsplit * B * PSTRIDE + (size_t)B * H) * sizeof(float);
        if (need <= ws_size) break;
        nsplit >>= 1;
    }
    const int chunk = S / nsplit;
    float* attn = ws + (size_t)nsplit * B * PSTRIDE;

    attn_pass1<<<dim3(nsplit, B), 256, 0, stream>>>(lstm, hidden, ws, chunk);
    attn_pass2<<<dim3(B), 256, 0, stream>>>(ws, nsplit, attn);
    attn_pass3<<<dim3(H / 8), 512, 0, stream>>>(hidden, W, bias, attn, out);
}

// Round 3
// 187.938 us; speedup vs baseline: 1.3859x; 1.3859x over previous
//
#include <hip/hip_runtime.h>
#include <cmath>

// B=64, S=2048, H=1024 fp32 attention + combine linear.
// lstm_output (512 MiB) dominates -> single-pass online softmax, read once.
// Round 3: pass1 = round-1 access pattern + depth-1 row prefetch (low VGPR,
//          no spill) + branch-deferred rescale; pass3 = 2 features per wave,
//          coalesced X reads (X stays L2-resident), shuffle reduce.

namespace {
constexpr int B = 64;
constexpr int S = 2048;
constexpr int H = 1024;
constexpr int NSPLIT = 16;                 // 1024 blocks in pass1
constexpr int CHUNK = S / NSPLIT;          // 128 rows per block
constexpr int ROWS_PER_WAVE = CHUNK / 4;   // 32
constexpr int PSTRIDE = H + 4;             // floats per partial record
constexpr size_t ATTN_OFF = (size_t)B * NSPLIT * PSTRIDE;  // floats
}

// ---------------- Pass 1: fused scores + online softmax + weighted sum ------
// Wave w of a block handles rows s0+w, s0+w+4, ... (same streams as round 1).
// LOADROW(R, I): row for per-wave iteration I -> 4 float4 per lane (64B).
#define LOADROW(R, I) do {                                                     \
    const float4* _p = base4 + (size_t)(I) * 1024;  /* 4 rows * 256 f4 */      \
    R[0] = _p[lane];       R[1] = _p[lane + 64];                               \
    R[2] = _p[lane + 128]; R[3] = _p[lane + 192];                              \
} while (0)

#define COMPUTEROW(R) do {                                                     \
    float _d = 0.f, _e = 0.f;                                                  \
    _d = fmaf(R[0].x, hv[0].x, _d); _d = fmaf(R[0].y, hv[0].y, _d);            \
    _d = fmaf(R[0].z, hv[0].z, _d); _d = fmaf(R[0].w, hv[0].w, _d);            \
    _e = fmaf(R[1].x, hv[1].x, _e); _e = fmaf(R[1].y, hv[1].y, _e);            \
    _e = fmaf(R[1].z, hv[1].z, _e); _e = fmaf(R[1].w, hv[1].w, _e);            \
    _d = fmaf(R[2].x, hv[2].x, _d); _d = fmaf(R[2].y, hv[2].y, _d);            \
    _d = fmaf(R[2].z, hv[2].z, _d); _d = fmaf(R[2].w, hv[2].w, _d);            \
    _e = fmaf(R[3].x, hv[3].x, _e); _e = fmaf(R[3].y, hv[3].y, _e);            \
    _e = fmaf(R[3].z, hv[3].z, _e); _e = fmaf(R[3].w, hv[3].w, _e);            \
    _d += _e;                                                                  \
    _Pragma("unroll")                                                          \
    for (int _o = 32; _o >= 1; _o >>= 1) _d += __shfl_xor(_d, _o);             \
    if (_d > m) {            /* wave-uniform: _d uniform after butterfly */    \
        const float _sc = __expf(m - _d);   /* exp(-inf)=0 on first row */     \
        l *= _sc;                                                              \
        _Pragma("unroll")                                                      \
        for (int _j = 0; _j < 4; ++_j) {                                       \
            acc[_j].x *= _sc; acc[_j].y *= _sc;                                \
            acc[_j].z *= _sc; acc[_j].w *= _sc;                                \
        }                                                                      \
        m = _d;                                                                \
    }                                                                          \
    const float _p = __expf(_d - m);                                           \
    l += _p;                                                                   \
    _Pragma("unroll")                                                          \
    for (int _j = 0; _j < 4; ++_j) {                                           \
        acc[_j].x = fmaf(_p, R[_j].x, acc[_j].x);                              \
        acc[_j].y = fmaf(_p, R[_j].y, acc[_j].y);                              \
        acc[_j].z = fmaf(_p, R[_j].z, acc[_j].z);                              \
        acc[_j].w = fmaf(_p, R[_j].w, acc[_j].w);                              \
    }                                                                          \
} while (0)

__global__ __launch_bounds__(256) void attn_pass1(
    const float* __restrict__ lstm,
    const float* __restrict__ hidden,
    float* __restrict__ ws)
{
    const int c    = blockIdx.x;
    const int b    = blockIdx.y;
    const int tid  = threadIdx.x;
    const int w    = tid >> 6;
    const int lane = tid & 63;

    const float4* hid4 = reinterpret_cast<const float4*>(hidden + (size_t)b * H);
    float4 hv[4];
#pragma unroll
    for (int j = 0; j < 4; ++j) hv[j] = hid4[lane + 64 * j];

    const int s0 = c * CHUNK;
    const float4* base4 =
        reinterpret_cast<const float4*>(lstm + ((size_t)b * S + s0 + w) * H);

    float m = -INFINITY, l = 0.0f;
    float4 acc[4];
#pragma unroll
    for (int j = 0; j < 4; ++j) acc[j] = make_float4(0.f, 0.f, 0.f, 0.f);

    float4 r[4], n[4];
    LOADROW(r, 0);
    for (int i = 0; i + 2 < ROWS_PER_WAVE; i += 2) {
        LOADROW(n, i + 1);        // prefetch while computing current
        COMPUTEROW(r);
        LOADROW(r, i + 2);
        COMPUTEROW(n);
    }
    LOADROW(n, ROWS_PER_WAVE - 1);
    COMPUTEROW(r);
    COMPUTEROW(n);

    // ---- combine the 4 waves of this block ----
    __shared__ float red_m[4];
    __shared__ float red_l[4];
    __shared__ float4 accbuf[4 * 256];   // 16 KiB

    if (lane == 0) { red_m[w] = m; red_l[w] = l; }
    __syncthreads();

    const float M = fmaxf(fmaxf(red_m[0], red_m[1]), fmaxf(red_m[2], red_m[3]));
    const float sc = __expf(m - M);
#pragma unroll
    for (int j = 0; j < 4; ++j) {
        float4 a = acc[j];
        accbuf[w * 256 + lane + 64 * j] =
            make_float4(a.x * sc, a.y * sc, a.z * sc, a.w * sc);
    }
    __syncthreads();

    const float L = red_l[0] * __expf(red_m[0] - M)
                  + red_l[1] * __expf(red_m[1] - M)
                  + red_l[2] * __expf(red_m[2] - M)
                  + red_l[3] * __expf(red_m[3] - M);

    float* part = ws + (size_t)(b * NSPLIT + c) * PSTRIDE;
    float4 s4 = accbuf[tid];
    {
        float4 t1 = accbuf[256 + tid];
        float4 t2 = accbuf[512 + tid];
        float4 t3 = accbuf[768 + tid];
        s4.x += t1.x + t2.x + t3.x;
        s4.y += t1.y + t2.y + t3.y;
        s4.z += t1.z + t2.z + t3.z;
        s4.w += t1.w + t2.w + t3.w;
    }
    reinterpret_cast<float4*>(part)[tid] = s4;
    if (tid == 0) { part[H] = M; part[H + 1] = L; }
}

// ---------------- Pass 2: merge NSPLIT partials per batch -------------------
__global__ __launch_bounds__(256) void attn_pass2(
    const float* __restrict__ ws, float* __restrict__ attn)
{
    const int b   = blockIdx.x;
    const int tid = threadIdx.x;

    __shared__ float sm[NSPLIT];
    __shared__ float sl[NSPLIT];
    if (tid < NSPLIT) {
        const float* part = ws + (size_t)(b * NSPLIT + tid) * PSTRIDE;
        sm[tid] = part[H];
        sl[tid] = part[H + 1];
    }
    __syncthreads();

    float M = -INFINITY;
#pragma unroll
    for (int i = 0; i < NSPLIT; ++i) M = fmaxf(M, sm[i]);
    float L = 0.0f;
#pragma unroll
    for (int i = 0; i < NSPLIT; ++i) L = fmaf(sl[i], __expf(sm[i] - M), L);
    const float inv = 1.0f / L;

    float4 a = make_float4(0.f, 0.f, 0.f, 0.f);
#pragma unroll
    for (int i = 0; i < NSPLIT; ++i) {
        const float f = __expf(sm[i] - M);   // recompute: no scratch array
        float4 v = reinterpret_cast<const float4*>(
            ws + (size_t)(b * NSPLIT + i) * PSTRIDE)[tid];
        a.x = fmaf(v.x, f, a.x);
        a.y = fmaf(v.y, f, a.y);
        a.z = fmaf(v.z, f, a.z);
        a.w = fmaf(v.w, f, a.w);
    }
    reinterpret_cast<float4*>(attn)[(size_t)b * (H / 4) + tid] =
        make_float4(a.x * inv, a.y * inv, a.z * inv, a.w * inv);
}

// ---------------- Pass 3: out = [hidden, attn] @ W^T + bias -----------------
// Wave = TWO output features (halves L2 re-reads of X). W rows in 64 VGPRs;
// lanes span k (coalesced, L2-hot X); butterfly reduce per (o,b).
__global__ __launch_bounds__(512) void attn_pass3(
    const float* __restrict__ hidden,
    const float* __restrict__ W,        // [H, 2H] row-major
    const float* __restrict__ bias,
    const float* __restrict__ attn,     // [B, H]
    float* __restrict__ out)            // [B, H]
{
    const int tid  = threadIdx.x;
    const int wid  = tid >> 6;
    const int lane = tid & 63;
    const int o0   = blockIdx.x * 16 + wid * 2;
    const int o1   = o0 + 1;

    const float4* W0 = reinterpret_cast<const float4*>(W + (size_t)o0 * (2 * H));
    const float4* W1 = reinterpret_cast<const float4*>(W + (size_t)o1 * (2 * H));
    float4 w0[8], w1[8];
#pragma unroll
    for (int j = 0; j < 8; ++j) w0[j] = W0[lane + 64 * j];
#pragma unroll
    for (int j = 0; j < 8; ++j) w1[j] = W1[lane + 64 * j];
    const float b0 = bias[o0];
    const float b1 = bias[o1];

    for (int b = 0; b < B; ++b) {
        const float4* h4 = reinterpret_cast<const float4*>(hidden + (size_t)b * H);
        const float4* a4 = reinterpret_cast<const float4*>(attn + (size_t)b * H);
        float s0 = 0.f, s1 = 0.f, t0 = 0.f, t1 = 0.f;
#pragma unroll
        for (int j = 0; j < 4; ++j) {
            float4 x = h4[lane + 64 * j];
            s0 = fmaf(x.x, w0[j].x, s0); s0 = fmaf(x.y, w0[j].y, s0);
            s0 = fmaf(x.z, w0[j].z, s0); s0 = fmaf(x.w, w0[j].w, s0);
            s1 = fmaf(x.x, w1[j].x, s1); s1 = fmaf(x.y, w1[j].y, s1);
            s1 = fmaf(x.z, w1[j].z, s1); s1 = fmaf(x.w, w1[j].w, s1);
            float4 y = a4[lane + 64 * j];
            t0 = fmaf(y.x, w0[j + 4].x, t0); t0 = fmaf(y.y, w0[j + 4].y, t0);
            t0 = fmaf(y.z, w0[j + 4].z, t0); t0 = fmaf(y.w, w0[j + 4].w, t0);
            t1 = fmaf(y.x, w1[j + 4].x, t1); t1 = fmaf(y.y, w1[j + 4].y, t1);
            t1 = fmaf(y.z, w1[j + 4].z, t1); t1 = fmaf(y.w, w1[j + 4].w, t1);
        }
        s0 += t0; s1 += t1;
#pragma unroll
        for (int off = 32; off >= 1; off >>= 1) {
            s0 += __shfl_xor(s0, off);
            s1 += __shfl_xor(s1, off);
        }
        if (lane == 0) {
            out[(size_t)b * H + o0] = s0 + b0;
            out[(size_t)b * H + o1] = s1 + b1;
        }
    }
}

extern "C" void kernel_launch(void* const* d_in, const int* in_sizes, int n_in,
                              void* d_out, int out_size, void* d_ws, size_t ws_size,
                              hipStream_t stream)
{
    const float* lstm   = (const float*)d_in[0];  // [B,S,H]
    const float* hidden = (const float*)d_in[1];  // [B,H]
    const float* W      = (const float*)d_in[2];  // [H,2H]
    const float* bias   = (const float*)d_in[3];  // [H]
    float* out = (float*)d_out;                   // [B,H]
    float* ws  = (float*)d_ws;                    // ~4.5 MB used
    float* attn = ws + ATTN_OFF;

    attn_pass1<<<dim3(NSPLIT, B), 256, 0, stream>>>(lstm, hidden, ws);
    attn_pass2<<<dim3(B), 256, 0, stream>>>(ws, attn);
    attn_pass3<<<dim3(H / 16), 512, 0, stream>>>(hidden, W, bias, attn, out);
}

// Round 4
// 185.626 us; speedup vs baseline: 1.4032x; 1.0125x over previous
//
#include <hip/hip_runtime.h>
#include <cmath>

// B=64, S=2048, H=1024 fp32 attention + combine linear.
// lstm_output (512 MiB) dominates -> single-pass online softmax, read once.
// Round 4: pass1 stages lstm tiles into LDS with global_load_lds (in-flight
// bytes cost no VGPRs; double-buffered 32 KB tiles; barrier drain = handoff).
// Compute = round-1's branch-free online softmax. Pass2/3 as round 3.

namespace {
constexpr int B = 64;
constexpr int S = 2048;
constexpr int H = 1024;                // floats per row (256 float4)
constexpr int NSPLIT = 8;              // 512 blocks -> exactly 2 per CU
constexpr int CHUNK = S / NSPLIT;      // 256 rows per block
constexpr int TR = 8;                  // rows per tile = 32 KB
constexpr int NT = CHUNK / TR;         // 32 tiles per block
constexpr int TF4 = TR * 256;          // float4 per tile buffer
constexpr int PSTRIDE = H + 4;         // floats per partial record
constexpr size_t ATTN_OFF = (size_t)B * NSPLIT * PSTRIDE;  // floats
}

// ---- async stage one 8-row tile (32 KB) into LDS: 8 issues/thread ----------
__device__ __forceinline__ void stage_tile(const float4* g, float4* l,
                                           int w, int lane)
{
#pragma unroll
    for (int it = 0; it < 8; ++it) {
        __builtin_amdgcn_global_load_lds(
            (__attribute__((address_space(1))) void*)(g + it * 256 + w * 64 + lane),
            (__attribute__((address_space(3))) void*)(l + it * 256 + w * 64),
            16, 0, 0);   // 16B/lane, wave-uniform LDS base + lane*16 (linear)
    }
}

// ---------------- Pass 1: fused scores + online softmax + weighted sum ------
__global__ __launch_bounds__(256) void attn_pass1(
    const float* __restrict__ lstm,
    const float* __restrict__ hidden,
    float* __restrict__ ws)
{
    __shared__ float4 lbuf[2 * TF4];       // 64 KB double buffer
    __shared__ float red_m[4];
    __shared__ float red_l[4];

    const int c    = blockIdx.x;
    const int b    = blockIdx.y;
    const int tid  = threadIdx.x;
    const int w    = tid >> 6;
    const int lane = tid & 63;

    const float4* hid4 = reinterpret_cast<const float4*>(hidden + (size_t)b * H);
    float4 hv[4];
#pragma unroll
    for (int j = 0; j < 4; ++j) hv[j] = hid4[lane + 64 * j];

    const float4* gbase =
        reinterpret_cast<const float4*>(lstm + ((size_t)b * S + c * CHUNK) * H);

    float m = -INFINITY, l = 0.0f;
    float4 acc[4];
#pragma unroll
    for (int j = 0; j < 4; ++j) acc[j] = make_float4(0.f, 0.f, 0.f, 0.f);

    stage_tile(gbase, lbuf, w, lane);      // prologue: tile 0 -> buf0

    for (int t = 0; t < NT; ++t) {
        __syncthreads();                   // tile t landed; buf[(t+1)&1] free
        if (t + 1 < NT)
            stage_tile(gbase + (size_t)(t + 1) * TF4,
                       lbuf + ((t + 1) & 1) * TF4, w, lane);

        const float4* cur = lbuf + (t & 1) * TF4;
        const float4* rA  = cur + (2 * w) * 256;   // wave w: rows 2w, 2w+1
        const float4* rB  = rA + 256;

        float4 a0 = rA[lane], a1 = rA[lane + 64],
               a2 = rA[lane + 128], a3 = rA[lane + 192];
        float4 b0 = rB[lane], b1 = rB[lane + 64],
               b2 = rB[lane + 128], b3 = rB[lane + 192];

        // two rows' dots, 4 independent chains of 8 FMAs
        float dA = 0.f, eA = 0.f, dB = 0.f, eB = 0.f;
        dA = fmaf(a0.x, hv[0].x, dA); dA = fmaf(a0.y, hv[0].y, dA);
        dA = fmaf(a0.z, hv[0].z, dA); dA = fmaf(a0.w, hv[0].w, dA);
        eA = fmaf(a1.x, hv[1].x, eA); eA = fmaf(a1.y, hv[1].y, eA);
        eA = fmaf(a1.z, hv[1].z, eA); eA = fmaf(a1.w, hv[1].w, eA);
        dA = fmaf(a2.x, hv[2].x, dA); dA = fmaf(a2.y, hv[2].y, dA);
        dA = fmaf(a2.z, hv[2].z, dA); dA = fmaf(a2.w, hv[2].w, dA);
        eA = fmaf(a3.x, hv[3].x, eA); eA = fmaf(a3.y, hv[3].y, eA);
        eA = fmaf(a3.z, hv[3].z, eA); eA = fmaf(a3.w, hv[3].w, eA);
        dB = fmaf(b0.x, hv[0].x, dB); dB = fmaf(b0.y, hv[0].y, dB);
        dB = fmaf(b0.z, hv[0].z, dB); dB = fmaf(b0.w, hv[0].w, dB);
        eB = fmaf(b1.x, hv[1].x, eB); eB = fmaf(b1.y, hv[1].y, eB);
        eB = fmaf(b1.z, hv[1].z, eB); eB = fmaf(b1.w, hv[1].w, eB);
        dB = fmaf(b2.x, hv[2].x, dB); dB = fmaf(b2.y, hv[2].y, dB);
        dB = fmaf(b2.z, hv[2].z, dB); dB = fmaf(b2.w, hv[2].w, dB);
        eB = fmaf(b3.x, hv[3].x, eB); eB = fmaf(b3.y, hv[3].y, eB);
        eB = fmaf(b3.z, hv[3].z, eB); eB = fmaf(b3.w, hv[3].w, eB);
        dA += eA; dB += eB;

#pragma unroll
        for (int o = 32; o >= 1; o >>= 1) {   // two interleaved butterflies
            dA += __shfl_xor(dA, o);
            dB += __shfl_xor(dB, o);
        }

        // branch-free online softmax update for both rows
        const float mx = fmaxf(m, fmaxf(dA, dB));
        const float sc = __expf(m - mx);      // exp(-inf)=0 on first tile
        const float pA = __expf(dA - mx);
        const float pB = __expf(dB - mx);
        l = fmaf(l, sc, pA + pB);
        m = mx;
#define ACC1(J, AV, BV)                                                        \
        acc[J].x = fmaf(acc[J].x, sc, fmaf(pA, AV.x, pB * BV.x));              \
        acc[J].y = fmaf(acc[J].y, sc, fmaf(pA, AV.y, pB * BV.y));              \
        acc[J].z = fmaf(acc[J].z, sc, fmaf(pA, AV.z, pB * BV.z));              \
        acc[J].w = fmaf(acc[J].w, sc, fmaf(pA, AV.w, pB * BV.w));
        ACC1(0, a0, b0) ACC1(1, a1, b1) ACC1(2, a2, b2) ACC1(3, a3, b3)
#undef ACC1
    }

    // ---- combine the 4 waves; reuse lbuf (staging done) as accbuf ----------
    __syncthreads();
    if (lane == 0) { red_m[w] = m; red_l[w] = l; }
    __syncthreads();

    const float M = fmaxf(fmaxf(red_m[0], red_m[1]), fmaxf(red_m[2], red_m[3]));
    const float sc = __expf(m - M);
    float4* accbuf = lbuf;                 // 16 KB of the 64 KB buffer
#pragma unroll
    for (int j = 0; j < 4; ++j) {
        float4 a = acc[j];
        accbuf[w * 256 + lane + 64 * j] =
            make_float4(a.x * sc, a.y * sc, a.z * sc, a.w * sc);
    }
    __syncthreads();

    const float L = red_l[0] * __expf(red_m[0] - M)
                  + red_l[1] * __expf(red_m[1] - M)
                  + red_l[2] * __expf(red_m[2] - M)
                  + red_l[3] * __expf(red_m[3] - M);

    float* part = ws + (size_t)(b * NSPLIT + c) * PSTRIDE;
    float4 s4 = accbuf[tid];
    {
        float4 t1 = accbuf[256 + tid];
        float4 t2 = accbuf[512 + tid];
        float4 t3 = accbuf[768 + tid];
        s4.x += t1.x + t2.x + t3.x;
        s4.y += t1.y + t2.y + t3.y;
        s4.z += t1.z + t2.z + t3.z;
        s4.w += t1.w + t2.w + t3.w;
    }
    reinterpret_cast<float4*>(part)[tid] = s4;
    if (tid == 0) { part[H] = M; part[H + 1] = L; }
}

// ---------------- Pass 2: merge NSPLIT partials per batch -------------------
__global__ __launch_bounds__(256) void attn_pass2(
    const float* __restrict__ ws, float* __restrict__ attn)
{
    const int b   = blockIdx.x;
    const int tid = threadIdx.x;

    __shared__ float sm[NSPLIT];
    __shared__ float sl[NSPLIT];
    if (tid < NSPLIT) {
        const float* part = ws + (size_t)(b * NSPLIT + tid) * PSTRIDE;
        sm[tid] = part[H];
        sl[tid] = part[H + 1];
    }
    __syncthreads();

    float M = -INFINITY;
#pragma unroll
    for (int i = 0; i < NSPLIT; ++i) M = fmaxf(M, sm[i]);
    float L = 0.0f;
#pragma unroll
    for (int i = 0; i < NSPLIT; ++i) L = fmaf(sl[i], __expf(sm[i] - M), L);
    const float inv = 1.0f / L;

    float4 a = make_float4(0.f, 0.f, 0.f, 0.f);
#pragma unroll
    for (int i = 0; i < NSPLIT; ++i) {
        const float f = __expf(sm[i] - M);
        float4 v = reinterpret_cast<const float4*>(
            ws + (size_t)(b * NSPLIT + i) * PSTRIDE)[tid];
        a.x = fmaf(v.x, f, a.x);
        a.y = fmaf(v.y, f, a.y);
        a.z = fmaf(v.z, f, a.z);
        a.w = fmaf(v.w, f, a.w);
    }
    reinterpret_cast<float4*>(attn)[(size_t)b * (H / 4) + tid] =
        make_float4(a.x * inv, a.y * inv, a.z * inv, a.w * inv);
}

// ---------------- Pass 3: out = [hidden, attn] @ W^T + bias -----------------
// Wave = two output features; W rows in VGPRs; lanes span k (coalesced,
// L2-hot X reads); butterfly reduce per (o,b).
__global__ __launch_bounds__(512) void attn_pass3(
    const float* __restrict__ hidden,
    const float* __restrict__ W,        // [H, 2H] row-major
    const float* __restrict__ bias,
    const float* __restrict__ attn,     // [B, H]
    float* __restrict__ out)            // [B, H]
{
    const int tid  = threadIdx.x;
    const int wid  = tid >> 6;
    const int lane = tid & 63;
    const int o0   = blockIdx.x * 16 + wid * 2;
    const int o1   = o0 + 1;

    const float4* W0 = reinterpret_cast<const float4*>(W + (size_t)o0 * (2 * H));
    const float4* W1 = reinterpret_cast<const float4*>(W + (size_t)o1 * (2 * H));
    float4 w0[8], w1[8];
#pragma unroll
    for (int j = 0; j < 8; ++j) w0[j] = W0[lane + 64 * j];
#pragma unroll
    for (int j = 0; j < 8; ++j) w1[j] = W1[lane + 64 * j];
    const float b0 = bias[o0];
    const float b1 = bias[o1];

    for (int b = 0; b < B; ++b) {
        const float4* h4 = reinterpret_cast<const float4*>(hidden + (size_t)b * H);
        const float4* a4 = reinterpret_cast<const float4*>(attn + (size_t)b * H);
        float s0 = 0.f, s1 = 0.f, t0 = 0.f, t1 = 0.f;
#pragma unroll
        for (int j = 0; j < 4; ++j) {
            float4 x = h4[lane + 64 * j];
            s0 = fmaf(x.x, w0[j].x, s0); s0 = fmaf(x.y, w0[j].y, s0);
            s0 = fmaf(x.z, w0[j].z, s0); s0 = fmaf(x.w, w0[j].w, s0);
            s1 = fmaf(x.x, w1[j].x, s1); s1 = fmaf(x.y, w1[j].y, s1);
            s1 = fmaf(x.z, w1[j].z, s1); s1 = fmaf(x.w, w1[j].w, s1);
            float4 y = a4[lane + 64 * j];
            t0 = fmaf(y.x, w0[j + 4].x, t0); t0 = fmaf(y.y, w0[j + 4].y, t0);
            t0 = fmaf(y.z, w0[j + 4].z, t0); t0 = fmaf(y.w, w0[j + 4].w, t0);
            t1 = fmaf(y.x, w1[j + 4].x, t1); t1 = fmaf(y.y, w1[j + 4].y, t1);
            t1 = fmaf(y.z, w1[j + 4].z, t1); t1 = fmaf(y.w, w1[j + 4].w, t1);
        }
        s0 += t0; s1 += t1;
#pragma unroll
        for (int off = 32; off >= 1; off >>= 1) {
            s0 += __shfl_xor(s0, off);
            s1 += __shfl_xor(s1, off);
        }
        if (lane == 0) {
            out[(size_t)b * H + o0] = s0 + b0;
            out[(size_t)b * H + o1] = s1 + b1;
        }
    }
}

extern "C" void kernel_launch(void* const* d_in, const int* in_sizes, int n_in,
                              void* d_out, int out_size, void* d_ws, size_t ws_size,
                              hipStream_t stream)
{
    const float* lstm   = (const float*)d_in[0];  // [B,S,H]
    const float* hidden = (const float*)d_in[1];  // [B,H]
    const float* W      = (const float*)d_in[2];  // [H,2H]
    const float* bias   = (const float*)d_in[3];  // [H]
    float* out = (float*)d_out;                   // [B,H]
    float* ws  = (float*)d_ws;                    // ~2.4 MB used
    float* attn = ws + ATTN_OFF;

    attn_pass1<<<dim3(NSPLIT, B), 256, 0, stream>>>(lstm, hidden, ws);
    attn_pass2<<<dim3(B), 256, 0, stream>>>(ws, attn);
    attn_pass3<<<dim3(H / 16), 512, 0, stream>>>(hidden, W, bias, attn, out);
}

// Round 5
// 121.603 us; speedup vs baseline: 2.1420x; 1.5265x over previous
//
#include <hip/hip_runtime.h>
#include <cmath>

// B=64, S=2048, H=1024 fp32 attention + combine linear.
// lstm_output (512 MiB) dominates -> single-pass online softmax, read once.
// Round 5: pass1 = counted-vmcnt deep pipeline (T3/T4): 16 KB tiles, 4 LDS
// buffers, depth-3 prefetch, s_waitcnt vmcnt(8) + raw s_barrier per tile --
// never drains to 0 in the loop (round-4's __syncthreads did, stalling the
// DRAM pipe every tile). Wave w stages & computes row w of each tile.
// Pass3 split over 4 batch-groups so all CUs participate.

namespace {
constexpr int B = 64;
constexpr int S = 2048;
constexpr int H = 1024;                // floats per row (256 float4)
constexpr int NSPLIT = 8;              // 512 blocks -> exactly 2 per CU
constexpr int CHUNK = S / NSPLIT;      // 256 rows per block
constexpr int TR = 4;                  // rows per tile (16 KB)
constexpr int NT = CHUNK / TR;         // 64 tiles per block
constexpr int TF4 = TR * 256;          // float4 per tile buffer
constexpr int NBUF = 4;                // 64 KB LDS double^2 buffer
constexpr int PSTRIDE = H + 4;         // floats per partial record
constexpr size_t ATTN_OFF = (size_t)B * NSPLIT * PSTRIDE;  // floats
}

// ---- stage one row (4 KB) into LDS: 4 x global_load_lds(16B/lane) ----------
__device__ __forceinline__ void stage_row(const float4* grow, float4* lrow,
                                          int lane)
{
#pragma unroll
    for (int it = 0; it < 4; ++it) {
        __builtin_amdgcn_global_load_lds(
            (__attribute__((address_space(1))) void*)(grow + it * 64 + lane),
            (__attribute__((address_space(3))) void*)(lrow + it * 64),
            16, 0, 0);   // LDS dest = wave-uniform base + lane*16 (linear)
    }
}

// ---------------- Pass 1: fused scores + online softmax + weighted sum ------
__global__ __launch_bounds__(256, 2) void attn_pass1(
    const float* __restrict__ lstm,
    const float* __restrict__ hidden,
    float* __restrict__ ws)
{
    __shared__ float4 lbuf[NBUF * TF4];    // 64 KB
    __shared__ float red_m[4];
    __shared__ float red_l[4];

    const int c    = blockIdx.x;
    const int b    = blockIdx.y;
    const int tid  = threadIdx.x;
    const int w    = tid >> 6;
    const int lane = tid & 63;

    const float4* hid4 = reinterpret_cast<const float4*>(hidden + (size_t)b * H);
    float4 hv[4];
#pragma unroll
    for (int j = 0; j < 4; ++j) hv[j] = hid4[lane + 64 * j];

    const float4* gbase =
        reinterpret_cast<const float4*>(lstm + ((size_t)b * S + c * CHUNK) * H);
    // wave w's row of tile t lives at gbase + (t*TR + w)*256

    float m = -INFINITY, l = 0.0f;
    float4 acc[4];
#pragma unroll
    for (int j = 0; j < 4; ++j) acc[j] = make_float4(0.f, 0.f, 0.f, 0.f);

    // prologue: 3 tiles in flight (12 loads/wave)
    stage_row(gbase + (0 * TR + w) * 256, lbuf + 0 * TF4 + w * 256, lane);
    stage_row(gbase + (1 * TR + w) * 256, lbuf + 1 * TF4 + w * 256, lane);
    stage_row(gbase + (2 * TR + w) * 256, lbuf + 2 * TF4 + w * 256, lane);

    for (int t = 0; t < NT; ++t) {
        // wait for tile t only; keep later tiles in flight (never vmcnt(0)
        // in steady state). 4 loads per tile per wave, in-order counting.
        if (t + 2 < NT)      asm volatile("s_waitcnt vmcnt(8)" ::: "memory");
        else if (t + 1 < NT) asm volatile("s_waitcnt vmcnt(4)" ::: "memory");
        else                 asm volatile("s_waitcnt vmcnt(0)" ::: "memory");
        __builtin_amdgcn_s_barrier();      // buf[(t+3)&3] (tile t-1) consumed
        asm volatile("" ::: "memory");

        if (t + 3 < NT)
            stage_row(gbase + ((t + 3) * TR + w) * 256,
                      lbuf + ((t + 3) & 3) * TF4 + w * 256, lane);

        const float4* r = lbuf + (t & 3) * TF4 + w * 256;   // own row
        float4 a0 = r[lane], a1 = r[lane + 64],
               a2 = r[lane + 128], a3 = r[lane + 192];

        float d = 0.f, e = 0.f;
        d = fmaf(a0.x, hv[0].x, d); d = fmaf(a0.y, hv[0].y, d);
        d = fmaf(a0.z, hv[0].z, d); d = fmaf(a0.w, hv[0].w, d);
        e = fmaf(a1.x, hv[1].x, e); e = fmaf(a1.y, hv[1].y, e);
        e = fmaf(a1.z, hv[1].z, e); e = fmaf(a1.w, hv[1].w, e);
        d = fmaf(a2.x, hv[2].x, d); d = fmaf(a2.y, hv[2].y, d);
        d = fmaf(a2.z, hv[2].z, d); d = fmaf(a2.w, hv[2].w, d);
        e = fmaf(a3.x, hv[3].x, e); e = fmaf(a3.y, hv[3].y, e);
        e = fmaf(a3.z, hv[3].z, e); e = fmaf(a3.w, hv[3].w, e);
        d += e;
#pragma unroll
        for (int o = 32; o >= 1; o >>= 1) d += __shfl_xor(d, o);

        // branch-free online softmax update (d wave-uniform)
        const float mx = fmaxf(m, d);
        const float sc = __expf(m - mx);   // exp(-inf)=0 on first tile
        const float p  = __expf(d - mx);
        l = fmaf(l, sc, p);
        m = mx;
        acc[0].x = fmaf(acc[0].x, sc, p * a0.x);
        acc[0].y = fmaf(acc[0].y, sc, p * a0.y);
        acc[0].z = fmaf(acc[0].z, sc, p * a0.z);
        acc[0].w = fmaf(acc[0].w, sc, p * a0.w);
        acc[1].x = fmaf(acc[1].x, sc, p * a1.x);
        acc[1].y = fmaf(acc[1].y, sc, p * a1.y);
        acc[1].z = fmaf(acc[1].z, sc, p * a1.z);
        acc[1].w = fmaf(acc[1].w, sc, p * a1.w);
        acc[2].x = fmaf(acc[2].x, sc, p * a2.x);
        acc[2].y = fmaf(acc[2].y, sc, p * a2.y);
        acc[2].z = fmaf(acc[2].z, sc, p * a2.z);
        acc[2].w = fmaf(acc[2].w, sc, p * a2.w);
        acc[3].x = fmaf(acc[3].x, sc, p * a3.x);
        acc[3].y = fmaf(acc[3].y, sc, p * a3.y);
        acc[3].z = fmaf(acc[3].z, sc, p * a3.z);
        acc[3].w = fmaf(acc[3].w, sc, p * a3.w);
    }

    // ---- combine the 4 waves; reuse lbuf (all staging drained) ------------
    __syncthreads();
    if (lane == 0) { red_m[w] = m; red_l[w] = l; }
    __syncthreads();

    const float M = fmaxf(fmaxf(red_m[0], red_m[1]), fmaxf(red_m[2], red_m[3]));
    const float sc = __expf(m - M);
    float4* accbuf = lbuf;
#pragma unroll
    for (int j = 0; j < 4; ++j) {
        float4 a = acc[j];
        accbuf[w * 256 + lane + 64 * j] =
            make_float4(a.x * sc, a.y * sc, a.z * sc, a.w * sc);
    }
    __syncthreads();

    const float L = red_l[0] * __expf(red_m[0] - M)
                  + red_l[1] * __expf(red_m[1] - M)
                  + red_l[2] * __expf(red_m[2] - M)
                  + red_l[3] * __expf(red_m[3] - M);

    float* part = ws + (size_t)(b * NSPLIT + c) * PSTRIDE;
    float4 s4 = accbuf[tid];
    {
        float4 t1 = accbuf[256 + tid];
        float4 t2 = accbuf[512 + tid];
        float4 t3 = accbuf[768 + tid];
        s4.x += t1.x + t2.x + t3.x;
        s4.y += t1.y + t2.y + t3.y;
        s4.z += t1.z + t2.z + t3.z;
        s4.w += t1.w + t2.w + t3.w;
    }
    reinterpret_cast<float4*>(part)[tid] = s4;
    if (tid == 0) { part[H] = M; part[H + 1] = L; }
}

// ---------------- Pass 2: merge NSPLIT partials per batch -------------------
__global__ __launch_bounds__(256) void attn_pass2(
    const float* __restrict__ ws, float* __restrict__ attn)
{
    const int b   = blockIdx.x;
    const int tid = threadIdx.x;

    __shared__ float sm[NSPLIT];
    __shared__ float sl[NSPLIT];
    if (tid < NSPLIT) {
        const float* part = ws + (size_t)(b * NSPLIT + tid) * PSTRIDE;
        sm[tid] = part[H];
        sl[tid] = part[H + 1];
    }
    __syncthreads();

    float M = -INFINITY;
#pragma unroll
    for (int i = 0; i < NSPLIT; ++i) M = fmaxf(M, sm[i]);
    float L = 0.0f;
#pragma unroll
    for (int i = 0; i < NSPLIT; ++i) L = fmaf(sl[i], __expf(sm[i] - M), L);
    const float inv = 1.0f / L;

    float4 a = make_float4(0.f, 0.f, 0.f, 0.f);
#pragma unroll
    for (int i = 0; i < NSPLIT; ++i) {
        const float f = __expf(sm[i] - M);
        float4 v = reinterpret_cast<const float4*>(
            ws + (size_t)(b * NSPLIT + i) * PSTRIDE)[tid];
        a.x = fmaf(v.x, f, a.x);
        a.y = fmaf(v.y, f, a.y);
        a.z = fmaf(v.z, f, a.z);
        a.w = fmaf(v.w, f, a.w);
    }
    reinterpret_cast<float4*>(attn)[(size_t)b * (H / 4) + tid] =
        make_float4(a.x * inv, a.y * inv, a.z * inv, a.w * inv);
}

// ---------------- Pass 3: out = [hidden, attn] @ W^T + bias -----------------
// Grid (H/16, 4): wave = 2 features, block-group handles 16 batches -> all
// CUs busy; W re-read 4x but L3-absorbed. Coalesced X reads, shuffle reduce.
__global__ __launch_bounds__(512) void attn_pass3(
    const float* __restrict__ hidden,
    const float* __restrict__ W,        // [H, 2H] row-major
    const float* __restrict__ bias,
    const float* __restrict__ attn,     // [B, H]
    float* __restrict__ out)            // [B, H]
{
    const int tid  = threadIdx.x;
    const int wid  = tid >> 6;
    const int lane = tid & 63;
    const int o0   = blockIdx.x * 16 + wid * 2;
    const int o1   = o0 + 1;
    const int blo  = blockIdx.y * (B / 4);
    const int bhi  = blo + (B / 4);

    const float4* W0 = reinterpret_cast<const float4*>(W + (size_t)o0 * (2 * H));
    const float4* W1 = reinterpret_cast<const float4*>(W + (size_t)o1 * (2 * H));
    float4 w0[8], w1[8];
#pragma unroll
    for (int j = 0; j < 8; ++j) w0[j] = W0[lane + 64 * j];
#pragma unroll
    for (int j = 0; j < 8; ++j) w1[j] = W1[lane + 64 * j];
    const float b0 = bias[o0];
    const float b1 = bias[o1];

    for (int b = blo; b < bhi; ++b) {
        const float4* h4 = reinterpret_cast<const float4*>(hidden + (size_t)b * H);
        const float4* a4 = reinterpret_cast<const float4*>(attn + (size_t)b * H);
        float s0 = 0.f, s1 = 0.f, t0 = 0.f, t1 = 0.f;
#pragma unroll
        for (int j = 0; j < 4; ++j) {
            float4 x = h4[lane + 64 * j];
            s0 = fmaf(x.x, w0[j].x, s0); s0 = fmaf(x.y, w0[j].y, s0);
            s0 = fmaf(x.z, w0[j].z, s0); s0 = fmaf(x.w, w0[j].w, s0);
            s1 = fmaf(x.x, w1[j].x, s1); s1 = fmaf(x.y, w1[j].y, s1);
            s1 = fmaf(x.z, w1[j].z, s1); s1 = fmaf(x.w, w1[j].w, s1);
            float4 y = a4[lane + 64 * j];
            t0 = fmaf(y.x, w0[j + 4].x, t0); t0 = fmaf(y.y, w0[j + 4].y, t0);
            t0 = fmaf(y.z, w0[j + 4].z, t0); t0 = fmaf(y.w, w0[j + 4].w, t0);
            t1 = fmaf(y.x, w1[j + 4].x, t1); t1 = fmaf(y.y, w1[j + 4].y, t1);
            t1 = fmaf(y.z, w1[j + 4].z, t1); t1 = fmaf(y.w, w1[j + 4].w, t1);
        }
        s0 += t0; s1 += t1;
#pragma unroll
        for (int off = 32; off >= 1; off >>= 1) {
            s0 += __shfl_xor(s0, off);
            s1 += __shfl_xor(s1, off);
        }
        if (lane == 0) {
            out[(size_t)b * H + o0] = s0 + b0;
            out[(size_t)b * H + o1] = s1 + b1;
        }
    }
}

extern "C" void kernel_launch(void* const* d_in, const int* in_sizes, int n_in,
                              void* d_out, int out_size, void* d_ws, size_t ws_size,
                              hipStream_t stream)
{
    const float* lstm   = (const float*)d_in[0];  // [B,S,H]
    const float* hidden = (const float*)d_in[1];  // [B,H]
    const float* W      = (const float*)d_in[2];  // [H,2H]
    const float* bias   = (const float*)d_in[3];  // [H]
    float* out = (float*)d_out;                   // [B,H]
    float* ws  = (float*)d_ws;                    // ~2.4 MB used
    float* attn = ws + ATTN_OFF;

    attn_pass1<<<dim3(NSPLIT, B), 256, 0, stream>>>(lstm, hidden, ws);
    attn_pass2<<<dim3(B), 256, 0, stream>>>(ws, attn);
    attn_pass3<<<dim3(H / 16, 4), 512, 0, stream>>>(hidden, W, bias, attn, out);
}

// Round 6
// 121.118 us; speedup vs baseline: 2.1505x; 1.0040x over previous
//
#include <hip/hip_runtime.h>
#include <cmath>

// B=64, S=2048, H=1024 fp32 attention + combine linear.
// lstm_output (512 MiB) dominates -> single-pass online softmax, read once.
// Round 6: pass1 drops the per-tile s_barrier entirely. Wave w stages AND
// consumes only its own LDS region (row w of each 4-row tile), so the only
// ordering needed is per-wave vmcnt (global_load_lds completion) + lgkmcnt
// (slot-reuse vs last iteration's ds_reads; in-order DS completion makes
// lgkmcnt(4) exact). Each wave free-runs as an independent depth-3 stream --
// no max-of-4-waves DRAM-jitter coupling per tile. Pass2/3 as round 5.

namespace {
constexpr int B = 64;
constexpr int S = 2048;
constexpr int H = 1024;                // floats per row (256 float4)
constexpr int NSPLIT = 8;              // 512 blocks -> exactly 2 per CU
constexpr int CHUNK = S / NSPLIT;      // 256 rows per block
constexpr int TR = 4;                  // rows per tile (one per wave)
constexpr int NT = CHUNK / TR;         // 64 tiles per block
constexpr int TF4 = TR * 256;          // float4 per tile buffer
constexpr int NBUF = 4;                // 64 KB LDS, per-wave 4-slot ring
constexpr int PSTRIDE = H + 4;         // floats per partial record
constexpr size_t ATTN_OFF = (size_t)B * NSPLIT * PSTRIDE;  // floats
}

// ---- stage one row (4 KB) into LDS: 4 x global_load_lds(16B/lane) ----------
__device__ __forceinline__ void stage_row(const float4* grow, float4* lrow,
                                          int lane)
{
#pragma unroll
    for (int it = 0; it < 4; ++it) {
        __builtin_amdgcn_global_load_lds(
            (__attribute__((address_space(1))) void*)(grow + it * 64 + lane),
            (__attribute__((address_space(3))) void*)(lrow + it * 64),
            16, 0, 0);   // LDS dest = wave-uniform base + lane*16 (linear)
    }
}

// One pipeline step for row index T (wave-local). WN = vmcnt wait literal.
// Order: wait own row -> ds_read it -> lgkmcnt(4) (prior slot reads drained;
// in-order DS completion, only our 4 fresh reads may remain) -> issue
// prefetch of row T+3 into the slot just freed -> compute.
#define P1_ITER(T, WN) do {                                                    \
    asm volatile("s_waitcnt vmcnt(" #WN ")" ::: "memory");                     \
    const float4* r = lbuf + ((T) & 3) * TF4 + w * 256;                        \
    float4 a0 = r[lane], a1 = r[lane + 64],                                    \
           a2 = r[lane + 128], a3 = r[lane + 192];                             \
    asm volatile("s_waitcnt lgkmcnt(4)" ::: "memory");                         \
    __builtin_amdgcn_sched_barrier(0);                                         \
    if ((T) + 3 < NT)                                                          \
        stage_row(gbase + (size_t)(((T) + 3) * TR + w) * 256,                  \
                  lbuf + (((T) + 3) & 3) * TF4 + w * 256, lane);               \
    float d = 0.f, e = 0.f;                                                    \
    d = fmaf(a0.x, hv[0].x, d); d = fmaf(a0.y, hv[0].y, d);                    \
    d = fmaf(a0.z, hv[0].z, d); d = fmaf(a0.w, hv[0].w, d);                    \
    e = fmaf(a1.x, hv[1].x, e); e = fmaf(a1.y, hv[1].y, e);                    \
    e = fmaf(a1.z, hv[1].z, e); e = fmaf(a1.w, hv[1].w, e);                    \
    d = fmaf(a2.x, hv[2].x, d); d = fmaf(a2.y, hv[2].y, d);                    \
    d = fmaf(a2.z, hv[2].z, d); d = fmaf(a2.w, hv[2].w, d);                    \
    e = fmaf(a3.x, hv[3].x, e); e = fmaf(a3.y, hv[3].y, e);                    \
    e = fmaf(a3.z, hv[3].z, e); e = fmaf(a3.w, hv[3].w, e);                    \
    d += e;                                                                    \
    _Pragma("unroll")                                                          \
    for (int o = 32; o >= 1; o >>= 1) d += __shfl_xor(d, o);                   \
    const float mx = fmaxf(m, d);                                              \
    const float sc = __expf(m - mx);   /* exp(-inf)=0 on first row */          \
    const float p  = __expf(d - mx);                                           \
    l = fmaf(l, sc, p);                                                        \
    m = mx;                                                                    \
    acc[0].x = fmaf(acc[0].x, sc, p * a0.x);                                   \
    acc[0].y = fmaf(acc[0].y, sc, p * a0.y);                                   \
    acc[0].z = fmaf(acc[0].z, sc, p * a0.z);                                   \
    acc[0].w = fmaf(acc[0].w, sc, p * a0.w);                                   \
    acc[1].x = fmaf(acc[1].x, sc, p * a1.x);                                   \
    acc[1].y = fmaf(acc[1].y, sc, p * a1.y);                                   \
    acc[1].z = fmaf(acc[1].z, sc, p * a1.z);                                   \
    acc[1].w = fmaf(acc[1].w, sc, p * a1.w);                                   \
    acc[2].x = fmaf(acc[2].x, sc, p * a2.x);                                   \
    acc[2].y = fmaf(acc[2].y, sc, p * a2.y);                                   \
    acc[2].z = fmaf(acc[2].z, sc, p * a2.z);                                   \
    acc[2].w = fmaf(acc[2].w, sc, p * a2.w);                                   \
    acc[3].x = fmaf(acc[3].x, sc, p * a3.x);                                   \
    acc[3].y = fmaf(acc[3].y, sc, p * a3.y);                                   \
    acc[3].z = fmaf(acc[3].z, sc, p * a3.z);                                   \
    acc[3].w = fmaf(acc[3].w, sc, p * a3.w);                                   \
} while (0)

// ---------------- Pass 1: fused scores + online softmax + weighted sum ------
__global__ __launch_bounds__(256, 2) void attn_pass1(
    const float* __restrict__ lstm,
    const float* __restrict__ hidden,
    float* __restrict__ ws)
{
    __shared__ float4 lbuf[NBUF * TF4];    // 64 KB
    __shared__ float red_m[4];
    __shared__ float red_l[4];

    const int c    = blockIdx.x;
    const int b    = blockIdx.y;
    const int tid  = threadIdx.x;
    const int w    = tid >> 6;
    const int lane = tid & 63;

    const float4* hid4 = reinterpret_cast<const float4*>(hidden + (size_t)b * H);
    float4 hv[4];
#pragma unroll
    for (int j = 0; j < 4; ++j) hv[j] = hid4[lane + 64 * j];

    const float4* gbase =
        reinterpret_cast<const float4*>(lstm + ((size_t)b * S + c * CHUNK) * H);
    // wave w's row of tile t: gbase + (t*TR + w)*256

    float m = -INFINITY, l = 0.0f;
    float4 acc[4];
#pragma unroll
    for (int j = 0; j < 4; ++j) acc[j] = make_float4(0.f, 0.f, 0.f, 0.f);

    // prologue: 3 rows in flight per wave (12 loads)
    stage_row(gbase + (size_t)(0 * TR + w) * 256, lbuf + 0 * TF4 + w * 256, lane);
    stage_row(gbase + (size_t)(1 * TR + w) * 256, lbuf + 1 * TF4 + w * 256, lane);
    stage_row(gbase + (size_t)(2 * TR + w) * 256, lbuf + 2 * TF4 + w * 256, lane);

    for (int t = 0; t < NT - 2; ++t) P1_ITER(t, 8);   // steady: rows t+1,t+2 out
    P1_ITER(NT - 2, 4);
    P1_ITER(NT - 1, 0);

    // ---- combine the 4 waves; reuse lbuf (all staging drained) ------------
    __syncthreads();
    if (lane == 0) { red_m[w] = m; red_l[w] = l; }
    __syncthreads();

    const float M = fmaxf(fmaxf(red_m[0], red_m[1]), fmaxf(red_m[2], red_m[3]));
    const float sc = __expf(m - M);
    float4* accbuf = lbuf;
#pragma unroll
    for (int j = 0; j < 4; ++j) {
        float4 a = acc[j];
        accbuf[w * 256 + lane + 64 * j] =
            make_float4(a.x * sc, a.y * sc, a.z * sc, a.w * sc);
    }
    __syncthreads();

    const float L = red_l[0] * __expf(red_m[0] - M)
                  + red_l[1] * __expf(red_m[1] - M)
                  + red_l[2] * __expf(red_m[2] - M)
                  + red_l[3] * __expf(red_m[3] - M);

    float* part = ws + (size_t)(b * NSPLIT + c) * PSTRIDE;
    float4 s4 = accbuf[tid];
    {
        float4 t1 = accbuf[256 + tid];
        float4 t2 = accbuf[512 + tid];
        float4 t3 = accbuf[768 + tid];
        s4.x += t1.x + t2.x + t3.x;
        s4.y += t1.y + t2.y + t3.y;
        s4.z += t1.z + t2.z + t3.z;
        s4.w += t1.w + t2.w + t3.w;
    }
    reinterpret_cast<float4*>(part)[tid] = s4;
    if (tid == 0) { part[H] = M; part[H + 1] = L; }
}

// ---------------- Pass 2: merge NSPLIT partials per batch -------------------
__global__ __launch_bounds__(256) void attn_pass2(
    const float* __restrict__ ws, float* __restrict__ attn)
{
    const int b   = blockIdx.x;
    const int tid = threadIdx.x;

    __shared__ float sm[NSPLIT];
    __shared__ float sl[NSPLIT];
    if (tid < NSPLIT) {
        const float* part = ws + (size_t)(b * NSPLIT + tid) * PSTRIDE;
        sm[tid] = part[H];
        sl[tid] = part[H + 1];
    }
    __syncthreads();

    float M = -INFINITY;
#pragma unroll
    for (int i = 0; i < NSPLIT; ++i) M = fmaxf(M, sm[i]);
    float L = 0.0f;
#pragma unroll
    for (int i = 0; i < NSPLIT; ++i) L = fmaf(sl[i], __expf(sm[i] - M), L);
    const float inv = 1.0f / L;

    float4 a = make_float4(0.f, 0.f, 0.f, 0.f);
#pragma unroll
    for (int i = 0; i < NSPLIT; ++i) {
        const float f = __expf(sm[i] - M);
        float4 v = reinterpret_cast<const float4*>(
            ws + (size_t)(b * NSPLIT + i) * PSTRIDE)[tid];
        a.x = fmaf(v.x, f, a.x);
        a.y = fmaf(v.y, f, a.y);
        a.z = fmaf(v.z, f, a.z);
        a.w = fmaf(v.w, f, a.w);
    }
    reinterpret_cast<float4*>(attn)[(size_t)b * (H / 4) + tid] =
        make_float4(a.x * inv, a.y * inv, a.z * inv, a.w * inv);
}

// ---------------- Pass 3: out = [hidden, attn] @ W^T + bias -----------------
// Grid (H/16, 4): wave = 2 features, block-group handles 16 batches -> all
// CUs busy; W re-read 4x but L3-absorbed. Coalesced X reads, shuffle reduce.
__global__ __launch_bounds__(512) void attn_pass3(
    const float* __restrict__ hidden,
    const float* __restrict__ W,        // [H, 2H] row-major
    const float* __restrict__ bias,
    const float* __restrict__ attn,     // [B, H]
    float* __restrict__ out)            // [B, H]
{
    const int tid  = threadIdx.x;
    const int wid  = tid >> 6;
    const int lane = tid & 63;
    const int o0   = blockIdx.x * 16 + wid * 2;
    const int o1   = o0 + 1;
    const int blo  = blockIdx.y * (B / 4);
    const int bhi  = blo + (B / 4);

    const float4* W0 = reinterpret_cast<const float4*>(W + (size_t)o0 * (2 * H));
    const float4* W1 = reinterpret_cast<const float4*>(W + (size_t)o1 * (2 * H));
    float4 w0[8], w1[8];
#pragma unroll
    for (int j = 0; j < 8; ++j) w0[j] = W0[lane + 64 * j];
#pragma unroll
    for (int j = 0; j < 8; ++j) w1[j] = W1[lane + 64 * j];
    const float b0 = bias[o0];
    const float b1 = bias[o1];

    for (int b = blo; b < bhi; ++b) {
        const float4* h4 = reinterpret_cast<const float4*>(hidden + (size_t)b * H);
        const float4* a4 = reinterpret_cast<const float4*>(attn + (size_t)b * H);
        float s0 = 0.f, s1 = 0.f, t0 = 0.f, t1 = 0.f;
#pragma unroll
        for (int j = 0; j < 4; ++j) {
            float4 x = h4[lane + 64 * j];
            s0 = fmaf(x.x, w0[j].x, s0); s0 = fmaf(x.y, w0[j].y, s0);
            s0 = fmaf(x.z, w0[j].z, s0); s0 = fmaf(x.w, w0[j].w, s0);
            s1 = fmaf(x.x, w1[j].x, s1); s1 = fmaf(x.y, w1[j].y, s1);
            s1 = fmaf(x.z, w1[j].z, s1); s1 = fmaf(x.w, w1[j].w, s1);
            float4 y = a4[lane + 64 * j];
            t0 = fmaf(y.x, w0[j + 4].x, t0); t0 = fmaf(y.y, w0[j + 4].y, t0);
            t0 = fmaf(y.z, w0[j + 4].z, t0); t0 = fmaf(y.w, w0[j + 4].w, t0);
            t1 = fmaf(y.x, w1[j + 4].x, t1); t1 = fmaf(y.y, w1[j + 4].y, t1);
            t1 = fmaf(y.z, w1[j + 4].z, t1); t1 = fmaf(y.w, w1[j + 4].w, t1);
        }
        s0 += t0; s1 += t1;
#pragma unroll
        for (int off = 32; off >= 1; off >>= 1) {
            s0 += __shfl_xor(s0, off);
            s1 += __shfl_xor(s1, off);
        }
        if (lane == 0) {
            out[(size_t)b * H + o0] = s0 + b0;
            out[(size_t)b * H + o1] = s1 + b1;
        }
    }
}

extern "C" void kernel_launch(void* const* d_in, const int* in_sizes, int n_in,
                              void* d_out, int out_size, void* d_ws, size_t ws_size,
                              hipStream_t stream)
{
    const float* lstm   = (const float*)d_in[0];  // [B,S,H]
    const float* hidden = (const float*)d_in[1];  // [B,H]
    const float* W      = (const float*)d_in[2];  // [H,2H]
    const float* bias   = (const float*)d_in[3];  // [H]
    float* out = (float*)d_out;                   // [B,H]
    float* ws  = (float*)d_ws;                    // ~2.4 MB used
    float* attn = ws + ATTN_OFF;

    attn_pass1<<<dim3(NSPLIT, B), 256, 0, stream>>>(lstm, hidden, ws);
    attn_pass2<<<dim3(B), 256, 0, stream>>>(ws, attn);
    attn_pass3<<<dim3(H / 16, 4), 512, 0, stream>>>(hidden, W, bias, attn, out);
}

// Round 7
// 114.760 us; speedup vs baseline: 2.2697x; 1.0554x over previous
//
#include <hip/hip_runtime.h>
#include <cmath>

// B=64, S=2048, H=1024 fp32 attention + combine linear.
// lstm_output (512 MiB) dominates -> single-pass online softmax, read once.
// Round 7: NSPLIT 8->16 (1024 blocks, 4 sequential per CU-slot) for dispatch
// load-balancing -- HBM jitter tail smoothed by backfill; block fill/drain
// bubbles hide under the co-resident block. Pass3 grid-y 4->8 (512 blocks x
// 8 batches) to halve its latency-bound span. Pipeline structure unchanged
// (per-wave free-run, depth-3 prefetch, counted vmcnt, 4-slot LDS ring).

namespace {
constexpr int B = 64;
constexpr int S = 2048;
constexpr int H = 1024;                // floats per row (256 float4)
constexpr int NSPLIT = 16;             // 1024 blocks -> 4 per CU-slot queue
constexpr int CHUNK = S / NSPLIT;      // 128 rows per block
constexpr int TR = 4;                  // rows per tile (one per wave)
constexpr int NT = CHUNK / TR;         // 32 tiles per block
constexpr int TF4 = TR * 256;          // float4 per tile buffer
constexpr int NBUF = 4;                // 64 KB LDS, per-wave 4-slot ring
constexpr int PSTRIDE = H + 4;         // floats per partial record
constexpr size_t ATTN_OFF = (size_t)B * NSPLIT * PSTRIDE;  // floats
}

// ---- stage one row (4 KB) into LDS: 4 x global_load_lds(16B/lane) ----------
__device__ __forceinline__ void stage_row(const float4* grow, float4* lrow,
                                          int lane)
{
#pragma unroll
    for (int it = 0; it < 4; ++it) {
        __builtin_amdgcn_global_load_lds(
            (__attribute__((address_space(1))) void*)(grow + it * 64 + lane),
            (__attribute__((address_space(3))) void*)(lrow + it * 64),
            16, 0, 0);   // LDS dest = wave-uniform base + lane*16 (linear)
    }
}

// One pipeline step for row index T (wave-local). WN = vmcnt wait literal.
#define P1_ITER(T, WN) do {                                                    \
    asm volatile("s_waitcnt vmcnt(" #WN ")" ::: "memory");                     \
    const float4* r = lbuf + ((T) & 3) * TF4 + w * 256;                        \
    float4 a0 = r[lane], a1 = r[lane + 64],                                    \
           a2 = r[lane + 128], a3 = r[lane + 192];                             \
    asm volatile("s_waitcnt lgkmcnt(4)" ::: "memory");                         \
    __builtin_amdgcn_sched_barrier(0);                                         \
    if ((T) + 3 < NT)                                                          \
        stage_row(gbase + (size_t)(((T) + 3) * TR + w) * 256,                  \
                  lbuf + (((T) + 3) & 3) * TF4 + w * 256, lane);               \
    float d = 0.f, e = 0.f;                                                    \
    d = fmaf(a0.x, hv[0].x, d); d = fmaf(a0.y, hv[0].y, d);                    \
    d = fmaf(a0.z, hv[0].z, d); d = fmaf(a0.w, hv[0].w, d);                    \
    e = fmaf(a1.x, hv[1].x, e); e = fmaf(a1.y, hv[1].y, e);                    \
    e = fmaf(a1.z, hv[1].z, e); e = fmaf(a1.w, hv[1].w, e);                    \
    d = fmaf(a2.x, hv[2].x, d); d = fmaf(a2.y, hv[2].y, d);                    \
    d = fmaf(a2.z, hv[2].z, d); d = fmaf(a2.w, hv[2].w, d);                    \
    e = fmaf(a3.x, hv[3].x, e); e = fmaf(a3.y, hv[3].y, e);                    \
    e = fmaf(a3.z, hv[3].z, e); e = fmaf(a3.w, hv[3].w, e);                    \
    d += e;                                                                    \
    _Pragma("unroll")                                                          \
    for (int o = 32; o >= 1; o >>= 1) d += __shfl_xor(d, o);                   \
    const float mx = fmaxf(m, d);                                              \
    const float sc = __expf(m - mx);   /* exp(-inf)=0 on first row */          \
    const float p  = __expf(d - mx);                                           \
    l = fmaf(l, sc, p);                                                        \
    m = mx;                                                                    \
    acc[0].x = fmaf(acc[0].x, sc, p * a0.x);                                   \
    acc[0].y = fmaf(acc[0].y, sc, p * a0.y);                                   \
    acc[0].z = fmaf(acc[0].z, sc, p * a0.z);                                   \
    acc[0].w = fmaf(acc[0].w, sc, p * a0.w);                                   \
    acc[1].x = fmaf(acc[1].x, sc, p * a1.x);                                   \
    acc[1].y = fmaf(acc[1].y, sc, p * a1.y);                                   \
    acc[1].z = fmaf(acc[1].z, sc, p * a1.z);                                   \
    acc[1].w = fmaf(acc[1].w, sc, p * a1.w);                                   \
    acc[2].x = fmaf(acc[2].x, sc, p * a2.x);                                   \
    acc[2].y = fmaf(acc[2].y, sc, p * a2.y);                                   \
    acc[2].z = fmaf(acc[2].z, sc, p * a2.z);                                   \
    acc[2].w = fmaf(acc[2].w, sc, p * a2.w);                                   \
    acc[3].x = fmaf(acc[3].x, sc, p * a3.x);                                   \
    acc[3].y = fmaf(acc[3].y, sc, p * a3.y);                                   \
    acc[3].z = fmaf(acc[3].z, sc, p * a3.z);                                   \
    acc[3].w = fmaf(acc[3].w, sc, p * a3.w);                                   \
} while (0)

// ---------------- Pass 1: fused scores + online softmax + weighted sum ------
__global__ __launch_bounds__(256, 2) void attn_pass1(
    const float* __restrict__ lstm,
    const float* __restrict__ hidden,
    float* __restrict__ ws)
{
    __shared__ float4 lbuf[NBUF * TF4];    // 64 KB
    __shared__ float red_m[4];
    __shared__ float red_l[4];

    const int c    = blockIdx.x;
    const int b    = blockIdx.y;
    const int tid  = threadIdx.x;
    const int w    = tid >> 6;
    const int lane = tid & 63;

    const float4* hid4 = reinterpret_cast<const float4*>(hidden + (size_t)b * H);
    float4 hv[4];
#pragma unroll
    for (int j = 0; j < 4; ++j) hv[j] = hid4[lane + 64 * j];

    const float4* gbase =
        reinterpret_cast<const float4*>(lstm + ((size_t)b * S + c * CHUNK) * H);
    // wave w's row of tile t: gbase + (t*TR + w)*256

    float m = -INFINITY, l = 0.0f;
    float4 acc[4];
#pragma unroll
    for (int j = 0; j < 4; ++j) acc[j] = make_float4(0.f, 0.f, 0.f, 0.f);

    // prologue: 3 rows in flight per wave (12 loads)
    stage_row(gbase + (size_t)(0 * TR + w) * 256, lbuf + 0 * TF4 + w * 256, lane);
    stage_row(gbase + (size_t)(1 * TR + w) * 256, lbuf + 1 * TF4 + w * 256, lane);
    stage_row(gbase + (size_t)(2 * TR + w) * 256, lbuf + 2 * TF4 + w * 256, lane);

    for (int t = 0; t < NT - 2; ++t) P1_ITER(t, 8);   // steady: 2 rows in flight
    P1_ITER(NT - 2, 4);
    P1_ITER(NT - 1, 0);

    // ---- combine the 4 waves; reuse lbuf (all staging drained) ------------
    __syncthreads();
    if (lane == 0) { red_m[w] = m; red_l[w] = l; }
    __syncthreads();

    const float M = fmaxf(fmaxf(red_m[0], red_m[1]), fmaxf(red_m[2], red_m[3]));
    const float sc = __expf(m - M);
    float4* accbuf = lbuf;
#pragma unroll
    for (int j = 0; j < 4; ++j) {
        float4 a = acc[j];
        accbuf[w * 256 + lane + 64 * j] =
            make_float4(a.x * sc, a.y * sc, a.z * sc, a.w * sc);
    }
    __syncthreads();

    const float L = red_l[0] * __expf(red_m[0] - M)
                  + red_l[1] * __expf(red_m[1] - M)
                  + red_l[2] * __expf(red_m[2] - M)
                  + red_l[3] * __expf(red_m[3] - M);

    float* part = ws + (size_t)(b * NSPLIT + c) * PSTRIDE;
    float4 s4 = accbuf[tid];
    {
        float4 t1 = accbuf[256 + tid];
        float4 t2 = accbuf[512 + tid];
        float4 t3 = accbuf[768 + tid];
        s4.x += t1.x + t2.x + t3.x;
        s4.y += t1.y + t2.y + t3.y;
        s4.z += t1.z + t2.z + t3.z;
        s4.w += t1.w + t2.w + t3.w;
    }
    reinterpret_cast<float4*>(part)[tid] = s4;
    if (tid == 0) { part[H] = M; part[H + 1] = L; }
}

// ---------------- Pass 2: merge NSPLIT partials per batch -------------------
__global__ __launch_bounds__(256) void attn_pass2(
    const float* __restrict__ ws, float* __restrict__ attn)
{
    const int b   = blockIdx.x;
    const int tid = threadIdx.x;

    __shared__ float sm[NSPLIT];
    __shared__ float sl[NSPLIT];
    if (tid < NSPLIT) {
        const float* part = ws + (size_t)(b * NSPLIT + tid) * PSTRIDE;
        sm[tid] = part[H];
        sl[tid] = part[H + 1];
    }
    __syncthreads();

    float M = -INFINITY;
#pragma unroll
    for (int i = 0; i < NSPLIT; ++i) M = fmaxf(M, sm[i]);
    float L = 0.0f;
#pragma unroll
    for (int i = 0; i < NSPLIT; ++i) L = fmaf(sl[i], __expf(sm[i] - M), L);
    const float inv = 1.0f / L;

    float4 a = make_float4(0.f, 0.f, 0.f, 0.f);
#pragma unroll
    for (int i = 0; i < NSPLIT; ++i) {
        const float f = __expf(sm[i] - M);
        float4 v = reinterpret_cast<const float4*>(
            ws + (size_t)(b * NSPLIT + i) * PSTRIDE)[tid];
        a.x = fmaf(v.x, f, a.x);
        a.y = fmaf(v.y, f, a.y);
        a.z = fmaf(v.z, f, a.z);
        a.w = fmaf(v.w, f, a.w);
    }
    reinterpret_cast<float4*>(attn)[(size_t)b * (H / 4) + tid] =
        make_float4(a.x * inv, a.y * inv, a.z * inv, a.w * inv);
}

// ---------------- Pass 3: out = [hidden, attn] @ W^T + bias -----------------
// Grid (H/16, 8): wave = 2 features, block handles 8 batches -> 512 blocks,
// all CUs busy; W re-read 8x (64 MB, L3-absorbed). Coalesced X reads.
__global__ __launch_bounds__(512) void attn_pass3(
    const float* __restrict__ hidden,
    const float* __restrict__ W,        // [H, 2H] row-major
    const float* __restrict__ bias,
    const float* __restrict__ attn,     // [B, H]
    float* __restrict__ out)            // [B, H]
{
    const int tid  = threadIdx.x;
    const int wid  = tid >> 6;
    const int lane = tid & 63;
    const int o0   = blockIdx.x * 16 + wid * 2;
    const int o1   = o0 + 1;
    const int blo  = blockIdx.y * (B / 8);
    const int bhi  = blo + (B / 8);

    const float4* W0 = reinterpret_cast<const float4*>(W + (size_t)o0 * (2 * H));
    const float4* W1 = reinterpret_cast<const float4*>(W + (size_t)o1 * (2 * H));
    float4 w0[8], w1[8];
#pragma unroll
    for (int j = 0; j < 8; ++j) w0[j] = W0[lane + 64 * j];
#pragma unroll
    for (int j = 0; j < 8; ++j) w1[j] = W1[lane + 64 * j];
    const float b0 = bias[o0];
    const float b1 = bias[o1];

    for (int b = blo; b < bhi; ++b) {
        const float4* h4 = reinterpret_cast<const float4*>(hidden + (size_t)b * H);
        const float4* a4 = reinterpret_cast<const float4*>(attn + (size_t)b * H);
        float s0 = 0.f, s1 = 0.f, t0 = 0.f, t1 = 0.f;
#pragma unroll
        for (int j = 0; j < 4; ++j) {
            float4 x = h4[lane + 64 * j];
            s0 = fmaf(x.x, w0[j].x, s0); s0 = fmaf(x.y, w0[j].y, s0);
            s0 = fmaf(x.z, w0[j].z, s0); s0 = fmaf(x.w, w0[j].w, s0);
            s1 = fmaf(x.x, w1[j].x, s1); s1 = fmaf(x.y, w1[j].y, s1);
            s1 = fmaf(x.z, w1[j].z, s1); s1 = fmaf(x.w, w1[j].w, s1);
            float4 y = a4[lane + 64 * j];
            t0 = fmaf(y.x, w0[j + 4].x, t0); t0 = fmaf(y.y, w0[j + 4].y, t0);
            t0 = fmaf(y.z, w0[j + 4].z, t0); t0 = fmaf(y.w, w0[j + 4].w, t0);
            t1 = fmaf(y.x, w1[j + 4].x, t1); t1 = fmaf(y.y, w1[j + 4].y, t1);
            t1 = fmaf(y.z, w1[j + 4].z, t1); t1 = fmaf(y.w, w1[j + 4].w, t1);
        }
        s0 += t0; s1 += t1;
#pragma unroll
        for (int off = 32; off >= 1; off >>= 1) {
            s0 += __shfl_xor(s0, off);
            s1 += __shfl_xor(s1, off);
        }
        if (lane == 0) {
            out[(size_t)b * H + o0] = s0 + b0;
            out[(size_t)b * H + o1] = s1 + b1;
        }
    }
}

extern "C" void kernel_launch(void* const* d_in, const int* in_sizes, int n_in,
                              void* d_out, int out_size, void* d_ws, size_t ws_size,
                              hipStream_t stream)
{
    const float* lstm   = (const float*)d_in[0];  // [B,S,H]
    const float* hidden = (const float*)d_in[1];  // [B,H]
    const float* W      = (const float*)d_in[2];  // [H,2H]
    const float* bias   = (const float*)d_in[3];  // [H]
    float* out = (float*)d_out;                   // [B,H]
    float* ws  = (float*)d_ws;                    // ~4.5 MB used
    float* attn = ws + ATTN_OFF;

    attn_pass1<<<dim3(NSPLIT, B), 256, 0, stream>>>(lstm, hidden, ws);
    attn_pass2<<<dim3(B), 256, 0, stream>>>(ws, attn);
    attn_pass3<<<dim3(H / 16, 8), 512, 0, stream>>>(hidden, W, bias, attn, out);
}